// Round 7
// baseline (2054.142 us; speedup 1.0000x reference)
//
#include <hip/hip_runtime.h>

#define HH 512
#define WW 512
#define HWSZ (HH * WW)

// LDS layout (float offsets). All float4-group bases are 16B-aligned.
#define O_W1 0      // 7x16
#define O_B1 112    // 16
#define O_W2 128    // 16x16
#define O_B2 384    // 16
#define O_W3 400    // 16x16
#define O_B3 656    // 16
#define O_W4 672    // 16x16
#define O_B4 928    // 16
#define O_W5 944    // 16x4 (padded from 16x3)
#define O_B5 1008   // 4 (padded from 3)
#define SW_TOT 1012

// Scheduler fence (mask 0 = nothing crosses). Bounds each layer's live set.
// Evidence: R4 (no fence, P=1) VGPR=256 + 4.3 GB scratch; R5 (fence, P=1)
// VGPR=40, no spill, 161 us. R6 (fence, P=4) overflowed on ACTIVATIONS
// (~172 live floats/region) -> 256 VGPR + 2.2 GB scratch. P=2 needs ~100
// live -> fits.
#define LAYER_FENCE() __builtin_amdgcn_sched_barrier(0)

// ---------------------------------------------------------------------------
// Pre-pass: transpose featuremap (C,H,W) -> (H,W,C): one bilinear corner = one
// aligned float4 load.
// ---------------------------------------------------------------------------
__global__ void fm_transpose(const float* __restrict__ fm, float* __restrict__ fmT) {
    int i = blockIdx.x * blockDim.x + threadIdx.x;
    if (i < HWSZ) {
        float4 v;
        v.x = fm[i];
        v.y = fm[HWSZ + i];
        v.z = fm[2 * HWSZ + i];
        v.w = fm[3 * HWSZ + i];
        reinterpret_cast<float4*>(fmT)[i] = v;
    }
}

// ---------------------------------------------------------------------------
// Fused grid_sample + MLP, 2 points/thread.
// R5 (P=1) measured 161 us = LDS-pipe model (253 uniform ds_read_b128/wave x
// ~6.2 cyc on the shared per-CU LDS port); VALU floor is ~52 us. P=2 halves
// waves -> LDS ~77 us, still above VALU -> expect LDS-bound ~80-95 us.
// Weights in LDS (uniform broadcast, conflict-free, structurally cannot
// scalarize into SGPRs — R1/R3 SGPR-spill/AGPR pathologies).
// ---------------------------------------------------------------------------
template <bool TR>
__global__ __launch_bounds__(256) void mlp_fused(
    const float* __restrict__ x, const float* __restrict__ fm,
    const float* __restrict__ W1, const float* __restrict__ b1,
    const float* __restrict__ W2, const float* __restrict__ b2,
    const float* __restrict__ W3, const float* __restrict__ b3,
    const float* __restrict__ W4, const float* __restrict__ b4,
    const float* __restrict__ W5, const float* __restrict__ b5,
    float* __restrict__ out, int n)
{
    __shared__ __align__(16) float sW[SW_TOT];
    const int tid = threadIdx.x;

    // ---- stage weights into LDS (one pass; 256 threads) ----
    if (tid < 112) sW[O_W1 + tid] = W1[tid];
    if (tid < 16) {
        sW[O_B1 + tid] = b1[tid];
        sW[O_B2 + tid] = b2[tid];
        sW[O_B3 + tid] = b3[tid];
        sW[O_B4 + tid] = b4[tid];
    }
    {   // W2/W3/W4: exactly one element per thread
        sW[O_W2 + tid] = W2[tid];
        sW[O_W3 + tid] = W3[tid];
        sW[O_W4 + tid] = W4[tid];
    }
    if (tid < 64) {  // W5 padded 16x3 -> 16x4
        int r = tid >> 2, c = tid & 3;
        sW[O_W5 + tid] = (c < 3) ? W5[r * 3 + c] : 0.f;
    }
    if (tid < 4) sW[O_B5 + tid] = (tid < 3) ? b5[tid] : 0.f;
    __syncthreads();

    const long long t  = (long long)blockIdx.x * blockDim.x + tid;
    const long long i0 = 2 * t;
    if (i0 >= n) return;  // after the barrier: safe
    const bool have2 = (i0 + 1 < n);

    // ---- load 2 points' coords (6 consecutive floats = 3x float2) ----
    float px[2][3];
    if (have2) {
        const float2* x2 = reinterpret_cast<const float2*>(x);
        float2 a = x2[3 * t], b = x2[3 * t + 1], c = x2[3 * t + 2];
        px[0][0] = a.x; px[0][1] = a.y; px[0][2] = b.x;
        px[1][0] = b.y; px[1][1] = c.x; px[1][2] = c.y;
    } else {
        px[0][0] = x[3 * i0]; px[0][1] = x[3 * i0 + 1]; px[0][2] = x[3 * i0 + 2];
        px[1][0] = px[0][0];  px[1][1] = px[0][1];      px[1][2] = px[0][2];
    }

    // ---- bilinear sample x2, border clamp (identical arithmetic to ref) ----
    float feat[2][4];
#pragma unroll
    for (int p = 0; p < 2; ++p) {
        float gx = px[p][0] * 2.f - 1.f;
        float gy = px[p][1] * 2.f - 1.f;
        float fx = ((gx + 1.f) * (float)WW - 1.f) * 0.5f;
        float fy = ((gy + 1.f) * (float)HH - 1.f) * 0.5f;
        fx = fminf(fmaxf(fx, 0.f), (float)(WW - 1));
        fy = fminf(fmaxf(fy, 0.f), (float)(HH - 1));
        float x0f = floorf(fx), y0f = floorf(fy);
        float wx = fx - x0f, wy = fy - y0f;
        int ix0 = (int)x0f, iy0 = (int)y0f;
        int ix1 = min(ix0 + 1, WW - 1);
        int iy1 = min(iy0 + 1, HH - 1);
        float w00 = (1.f - wy) * (1.f - wx);
        float w01 = (1.f - wy) * wx;
        float w10 = wy * (1.f - wx);
        float w11 = wy * wx;
        if (TR) {
            const float4* fmT = reinterpret_cast<const float4*>(fm);
            float4 v00 = fmT[iy0 * WW + ix0];
            float4 v01 = fmT[iy0 * WW + ix1];
            float4 v10 = fmT[iy1 * WW + ix0];
            float4 v11 = fmT[iy1 * WW + ix1];
            feat[p][0] = v00.x * w00 + v01.x * w01 + v10.x * w10 + v11.x * w11;
            feat[p][1] = v00.y * w00 + v01.y * w01 + v10.y * w10 + v11.y * w11;
            feat[p][2] = v00.z * w00 + v01.z * w01 + v10.z * w10 + v11.z * w11;
            feat[p][3] = v00.w * w00 + v01.w * w01 + v10.w * w10 + v11.w * w11;
        } else {
#pragma unroll
            for (int ch = 0; ch < 4; ++ch) {
                const float* f = fm + ch * HWSZ;
                feat[p][ch] = f[iy0 * WW + ix0] * w00 + f[iy0 * WW + ix1] * w01 +
                              f[iy1 * WW + ix0] * w10 + f[iy1 * WW + ix1] * w11;
            }
        }
    }

    // ---- MLP from LDS weights; one ds_read_b128 feeds 8 FMAs ----
    const float4* sW1v = reinterpret_cast<const float4*>(sW + O_W1);
    const float4* sB1v = reinterpret_cast<const float4*>(sW + O_B1);
    const float4* sW2v = reinterpret_cast<const float4*>(sW + O_W2);
    const float4* sB2v = reinterpret_cast<const float4*>(sW + O_B2);
    const float4* sW3v = reinterpret_cast<const float4*>(sW + O_W3);
    const float4* sB3v = reinterpret_cast<const float4*>(sW + O_B3);
    const float4* sW4v = reinterpret_cast<const float4*>(sW + O_W4);
    const float4* sB4v = reinterpret_cast<const float4*>(sW + O_B4);
    const float4* sW5v = reinterpret_cast<const float4*>(sW + O_W5);

    float in[2][7];
#pragma unroll
    for (int p = 0; p < 2; ++p) {
        in[p][0] = px[p][0]; in[p][1] = px[p][1]; in[p][2] = px[p][2];
        in[p][3] = feat[p][0]; in[p][4] = feat[p][1];
        in[p][5] = feat[p][2]; in[p][6] = feat[p][3];
    }
    float h[2][16], g[2][16];

    LAYER_FENCE();
    // layer 1: 7 -> 16, relu
#pragma unroll
    for (int jg = 0; jg < 4; ++jg) {
        float4 bb = sB1v[jg];
        float4 a0 = bb, a1 = bb;
#pragma unroll
        for (int k = 0; k < 7; ++k) {
            float4 w = sW1v[k * 4 + jg];
            float u0 = in[0][k], u1 = in[1][k];
            a0.x = fmaf(u0, w.x, a0.x); a1.x = fmaf(u1, w.x, a1.x);
            a0.y = fmaf(u0, w.y, a0.y); a1.y = fmaf(u1, w.y, a1.y);
            a0.z = fmaf(u0, w.z, a0.z); a1.z = fmaf(u1, w.z, a1.z);
            a0.w = fmaf(u0, w.w, a0.w); a1.w = fmaf(u1, w.w, a1.w);
        }
        h[0][jg * 4 + 0] = fmaxf(a0.x, 0.f); h[1][jg * 4 + 0] = fmaxf(a1.x, 0.f);
        h[0][jg * 4 + 1] = fmaxf(a0.y, 0.f); h[1][jg * 4 + 1] = fmaxf(a1.y, 0.f);
        h[0][jg * 4 + 2] = fmaxf(a0.z, 0.f); h[1][jg * 4 + 2] = fmaxf(a1.z, 0.f);
        h[0][jg * 4 + 3] = fmaxf(a0.w, 0.f); h[1][jg * 4 + 3] = fmaxf(a1.w, 0.f);
    }
    LAYER_FENCE();

#define LAYER16(WV, BV, src, dst)                                      \
    _Pragma("unroll")                                                  \
    for (int jg = 0; jg < 4; ++jg) {                                   \
        float4 bb = (BV)[jg];                                          \
        float4 a0 = bb, a1 = bb;                                       \
        _Pragma("unroll")                                              \
        for (int k = 0; k < 16; ++k) {                                 \
            float4 w = (WV)[k * 4 + jg];                               \
            float u0 = (src)[0][k], u1 = (src)[1][k];                  \
            a0.x = fmaf(u0, w.x, a0.x); a1.x = fmaf(u1, w.x, a1.x);    \
            a0.y = fmaf(u0, w.y, a0.y); a1.y = fmaf(u1, w.y, a1.y);    \
            a0.z = fmaf(u0, w.z, a0.z); a1.z = fmaf(u1, w.z, a1.z);    \
            a0.w = fmaf(u0, w.w, a0.w); a1.w = fmaf(u1, w.w, a1.w);    \
        }                                                              \
        (dst)[0][jg * 4 + 0] = fmaxf(a0.x, 0.f); (dst)[1][jg * 4 + 0] = fmaxf(a1.x, 0.f); \
        (dst)[0][jg * 4 + 1] = fmaxf(a0.y, 0.f); (dst)[1][jg * 4 + 1] = fmaxf(a1.y, 0.f); \
        (dst)[0][jg * 4 + 2] = fmaxf(a0.z, 0.f); (dst)[1][jg * 4 + 2] = fmaxf(a1.z, 0.f); \
        (dst)[0][jg * 4 + 3] = fmaxf(a0.w, 0.f); (dst)[1][jg * 4 + 3] = fmaxf(a1.w, 0.f); \
    }

    LAYER16(sW2v, sB2v, h, g)
    LAYER_FENCE();
    LAYER16(sW3v, sB3v, g, h)
    LAYER_FENCE();
    LAYER16(sW4v, sB4v, h, g)
    LAYER_FENCE();
#undef LAYER16

    // layer 5: 16 -> 3 (padded to 4), no relu
    float4 bb5 = *reinterpret_cast<const float4*>(sW + O_B5);
    float4 a0 = bb5, a1 = bb5;
#pragma unroll
    for (int k = 0; k < 16; ++k) {
        float4 w = sW5v[k];
        float u0 = g[0][k], u1 = g[1][k];
        a0.x = fmaf(u0, w.x, a0.x); a1.x = fmaf(u1, w.x, a1.x);
        a0.y = fmaf(u0, w.y, a0.y); a1.y = fmaf(u1, w.y, a1.y);
        a0.z = fmaf(u0, w.z, a0.z); a1.z = fmaf(u1, w.z, a1.z);
    }

    // ---- store 2 points (6 floats = 3x float2) ----
    if (have2) {
        float2* out2 = reinterpret_cast<float2*>(out);
        out2[3 * t]     = make_float2(a0.x, a0.y);
        out2[3 * t + 1] = make_float2(a0.z, a1.x);
        out2[3 * t + 2] = make_float2(a1.y, a1.z);
    } else {
        out[3 * i0] = a0.x; out[3 * i0 + 1] = a0.y; out[3 * i0 + 2] = a0.z;
    }
}

extern "C" void kernel_launch(void* const* d_in, const int* in_sizes, int n_in,
                              void* d_out, int out_size, void* d_ws, size_t ws_size,
                              hipStream_t stream) {
    const float* x  = (const float*)d_in[0];
    const float* fm = (const float*)d_in[1];
    const float* W1 = (const float*)d_in[2];
    const float* b1 = (const float*)d_in[3];
    const float* W2 = (const float*)d_in[4];
    const float* b2 = (const float*)d_in[5];
    const float* W3 = (const float*)d_in[6];
    const float* b3 = (const float*)d_in[7];
    const float* W4 = (const float*)d_in[8];
    const float* b4 = (const float*)d_in[9];
    const float* W5 = (const float*)d_in[10];
    const float* b5 = (const float*)d_in[11];
    float* out = (float*)d_out;

    const int n = in_sizes[0] / 3;  // 4,000,000 points
    const int block = 256;
    const long long threads = ((long long)n + 1) / 2;
    const int grid = (int)((threads + block - 1) / block);

    const size_t need = (size_t)HWSZ * 4 * sizeof(float);  // 4 MB
    if (ws_size >= need) {
        float* fmT = (float*)d_ws;
        fm_transpose<<<(HWSZ + 255) / 256, 256, 0, stream>>>(fm, fmT);
        mlp_fused<true><<<grid, block, 0, stream>>>(x, fmT, W1, b1, W2, b2, W3, b3,
                                                    W4, b4, W5, b5, out, n);
    } else {
        mlp_fused<false><<<grid, block, 0, stream>>>(x, fm, W1, b1, W2, b2, W3, b3,
                                                     W4, b4, W5, b5, out, n);
    }
}

// Round 8
// 2034.272 us; speedup vs baseline: 1.0098x; 1.0098x over previous
//
#include <hip/hip_runtime.h>

#define HH 512
#define WW 512
#define HWSZ (HH * WW)

// LDS layout (float offsets). All float4-group bases are 16B-aligned.
#define O_W1 0      // 7x16
#define O_B1 112    // 16
#define O_W2 128    // 16x16
#define O_B2 384    // 16
#define O_W3 400    // 16x16
#define O_B3 656    // 16
#define O_W4 672    // 16x16
#define O_B4 928    // 16
#define O_W5 944    // 16x4 (padded from 16x3)
#define O_B5 1008   // 4 (padded from 3)
#define SW_TOT 1012

// Scheduler fence (mask 0 = nothing crosses). Bounds each layer's weight
// live-range (R5: VGPR=40, zero scratch with this + 1-D locals).
#define LAYER_FENCE() __builtin_amdgcn_sched_barrier(0)

// SPILL POST-MORTEM (R4/R6/R7): every kernel that used 2-D local activation
// arrays (h[2][16], in[4][7]...) compiled to VGPR=256 + GB-scale scratch —
// the aggregates themselves were lowered to scratch (SROA failure), not an
// allocator overflow. Clean compiles (R1/R3/R5) all used 1-D arrays/scalars.
// => This kernel uses ONLY named float4 variables for activations.

__global__ void fm_transpose(const float* __restrict__ fm, float* __restrict__ fmT) {
    int i = blockIdx.x * blockDim.x + threadIdx.x;
    if (i < HWSZ) {
        float4 v;
        v.x = fm[i];
        v.y = fm[HWSZ + i];
        v.z = fm[2 * HWSZ + i];
        v.w = fm[3 * HWSZ + i];
        reinterpret_cast<float4*>(fmT)[i] = v;
    }
}

#define FMA4(acc, w, u) \
    acc.x = fmaf((u), (w).x, acc.x); \
    acc.y = fmaf((u), (w).y, acc.y); \
    acc.z = fmaf((u), (w).z, acc.z); \
    acc.w = fmaf((u), (w).w, acc.w);

#define RELU4(a) \
    a.x = fmaxf(a.x, 0.f); a.y = fmaxf(a.y, 0.f); \
    a.z = fmaxf(a.z, 0.f); a.w = fmaxf(a.w, 0.f);

// One float4 column-group (4 output cols) of a 16->16 layer, for 2 points.
// Each ds_read_b128 (w) feeds 8 FMAs.
#define JG_L16(WV, BV, jg, sA0, sA1, sA2, sA3, sB0, sB1, sB2, sB3, dA, dB) { \
    float4 accA = (BV)[jg]; float4 accB = accA; float4 w;                    \
    w = (WV)[ 0 * 4 + (jg)]; FMA4(accA, w, (sA0).x) FMA4(accB, w, (sB0).x)   \
    w = (WV)[ 1 * 4 + (jg)]; FMA4(accA, w, (sA0).y) FMA4(accB, w, (sB0).y)   \
    w = (WV)[ 2 * 4 + (jg)]; FMA4(accA, w, (sA0).z) FMA4(accB, w, (sB0).z)   \
    w = (WV)[ 3 * 4 + (jg)]; FMA4(accA, w, (sA0).w) FMA4(accB, w, (sB0).w)   \
    w = (WV)[ 4 * 4 + (jg)]; FMA4(accA, w, (sA1).x) FMA4(accB, w, (sB1).x)   \
    w = (WV)[ 5 * 4 + (jg)]; FMA4(accA, w, (sA1).y) FMA4(accB, w, (sB1).y)   \
    w = (WV)[ 6 * 4 + (jg)]; FMA4(accA, w, (sA1).z) FMA4(accB, w, (sB1).z)   \
    w = (WV)[ 7 * 4 + (jg)]; FMA4(accA, w, (sA1).w) FMA4(accB, w, (sB1).w)   \
    w = (WV)[ 8 * 4 + (jg)]; FMA4(accA, w, (sA2).x) FMA4(accB, w, (sB2).x)   \
    w = (WV)[ 9 * 4 + (jg)]; FMA4(accA, w, (sA2).y) FMA4(accB, w, (sB2).y)   \
    w = (WV)[10 * 4 + (jg)]; FMA4(accA, w, (sA2).z) FMA4(accB, w, (sB2).z)   \
    w = (WV)[11 * 4 + (jg)]; FMA4(accA, w, (sA2).w) FMA4(accB, w, (sB2).w)   \
    w = (WV)[12 * 4 + (jg)]; FMA4(accA, w, (sA3).x) FMA4(accB, w, (sB3).x)   \
    w = (WV)[13 * 4 + (jg)]; FMA4(accA, w, (sA3).y) FMA4(accB, w, (sB3).y)   \
    w = (WV)[14 * 4 + (jg)]; FMA4(accA, w, (sA3).z) FMA4(accB, w, (sB3).z)   \
    w = (WV)[15 * 4 + (jg)]; FMA4(accA, w, (sA3).w) FMA4(accB, w, (sB3).w)   \
    RELU4(accA) RELU4(accB) (dA) = accA; (dB) = accB; }

#define LAYER16S(WV, BV, sA0, sA1, sA2, sA3, sB0, sB1, sB2, sB3,             \
                 dA0, dA1, dA2, dA3, dB0, dB1, dB2, dB3)                     \
    JG_L16(WV, BV, 0, sA0, sA1, sA2, sA3, sB0, sB1, sB2, sB3, dA0, dB0)      \
    JG_L16(WV, BV, 1, sA0, sA1, sA2, sA3, sB0, sB1, sB2, sB3, dA1, dB1)      \
    JG_L16(WV, BV, 2, sA0, sA1, sA2, sA3, sB0, sB1, sB2, sB3, dA2, dB2)      \
    JG_L16(WV, BV, 3, sA0, sA1, sA2, sA3, sB0, sB1, sB2, sB3, dA3, dB3)

template <bool TR>
__global__ __launch_bounds__(256) void mlp_fused(
    const float* __restrict__ x, const float* __restrict__ fm,
    const float* __restrict__ W1, const float* __restrict__ b1,
    const float* __restrict__ W2, const float* __restrict__ b2,
    const float* __restrict__ W3, const float* __restrict__ b3,
    const float* __restrict__ W4, const float* __restrict__ b4,
    const float* __restrict__ W5, const float* __restrict__ b5,
    float* __restrict__ out, int n)
{
    __shared__ __align__(16) float sW[SW_TOT];
    const int tid = threadIdx.x;

    // ---- stage weights into LDS ----
    if (tid < 112) sW[O_W1 + tid] = W1[tid];
    if (tid < 16) {
        sW[O_B1 + tid] = b1[tid];
        sW[O_B2 + tid] = b2[tid];
        sW[O_B3 + tid] = b3[tid];
        sW[O_B4 + tid] = b4[tid];
    }
    sW[O_W2 + tid] = W2[tid];
    sW[O_W3 + tid] = W3[tid];
    sW[O_W4 + tid] = W4[tid];
    if (tid < 64) {
        int r = tid >> 2, c = tid & 3;
        sW[O_W5 + tid] = (c < 3) ? W5[r * 3 + c] : 0.f;
    }
    if (tid < 4) sW[O_B5 + tid] = (tid < 3) ? b5[tid] : 0.f;
    __syncthreads();

    const long long t  = (long long)blockIdx.x * blockDim.x + tid;
    const long long i0 = 2 * t;
    if (i0 >= n) return;
    const bool have2 = (i0 + 1 < n);

    // ---- coords: pure scalars ----
    float p0x, p0y, p0z, p1x, p1y, p1z;
    if (have2) {
        const float2* x2 = reinterpret_cast<const float2*>(x);
        float2 a = x2[3 * t], b = x2[3 * t + 1], c = x2[3 * t + 2];
        p0x = a.x; p0y = a.y; p0z = b.x;
        p1x = b.y; p1y = c.x; p1z = c.y;
    } else {
        p0x = x[3 * i0]; p0y = x[3 * i0 + 1]; p0z = x[3 * i0 + 2];
        p1x = p0x; p1y = p0y; p1z = p0z;
    }

    // ---- bilinear sample (identical arithmetic to reference) ----
#define BILERP(PX, PY, FOUT) {                                               \
    float gx = (PX) * 2.f - 1.f;                                             \
    float gy = (PY) * 2.f - 1.f;                                             \
    float fx = ((gx + 1.f) * (float)WW - 1.f) * 0.5f;                        \
    float fy = ((gy + 1.f) * (float)HH - 1.f) * 0.5f;                        \
    fx = fminf(fmaxf(fx, 0.f), (float)(WW - 1));                             \
    fy = fminf(fmaxf(fy, 0.f), (float)(HH - 1));                             \
    float x0f = floorf(fx), y0f = floorf(fy);                                \
    float wx = fx - x0f, wy = fy - y0f;                                      \
    int ix0 = (int)x0f, iy0 = (int)y0f;                                      \
    int ix1 = min(ix0 + 1, WW - 1);                                          \
    int iy1 = min(iy0 + 1, HH - 1);                                          \
    float w00 = (1.f - wy) * (1.f - wx);                                     \
    float w01 = (1.f - wy) * wx;                                             \
    float w10 = wy * (1.f - wx);                                             \
    float w11 = wy * wx;                                                     \
    if (TR) {                                                                \
        const float4* fmT = reinterpret_cast<const float4*>(fm);             \
        float4 v00 = fmT[iy0 * WW + ix0];                                    \
        float4 v01 = fmT[iy0 * WW + ix1];                                    \
        float4 v10 = fmT[iy1 * WW + ix0];                                    \
        float4 v11 = fmT[iy1 * WW + ix1];                                    \
        FOUT.x = v00.x * w00 + v01.x * w01 + v10.x * w10 + v11.x * w11;      \
        FOUT.y = v00.y * w00 + v01.y * w01 + v10.y * w10 + v11.y * w11;      \
        FOUT.z = v00.z * w00 + v01.z * w01 + v10.z * w10 + v11.z * w11;      \
        FOUT.w = v00.w * w00 + v01.w * w01 + v10.w * w10 + v11.w * w11;      \
    } else {                                                                 \
        const float* f0 = fm;                                                \
        const float* f1 = fm + HWSZ;                                         \
        const float* f2 = fm + 2 * HWSZ;                                     \
        const float* f3 = fm + 3 * HWSZ;                                     \
        int a00 = iy0 * WW + ix0, a01 = iy0 * WW + ix1;                      \
        int a10 = iy1 * WW + ix0, a11 = iy1 * WW + ix1;                      \
        FOUT.x = f0[a00] * w00 + f0[a01] * w01 + f0[a10] * w10 + f0[a11] * w11; \
        FOUT.y = f1[a00] * w00 + f1[a01] * w01 + f1[a10] * w10 + f1[a11] * w11; \
        FOUT.z = f2[a00] * w00 + f2[a01] * w01 + f2[a10] * w10 + f2[a11] * w11; \
        FOUT.w = f3[a00] * w00 + f3[a01] * w01 + f3[a10] * w10 + f3[a11] * w11; \
    } }

    float4 fA, fB;
    BILERP(p0x, p0y, fA)
    BILERP(p1x, p1y, fB)
#undef BILERP

    const float4* sW1v = reinterpret_cast<const float4*>(sW + O_W1);
    const float4* sB1v = reinterpret_cast<const float4*>(sW + O_B1);
    const float4* sW2v = reinterpret_cast<const float4*>(sW + O_W2);
    const float4* sB2v = reinterpret_cast<const float4*>(sW + O_B2);
    const float4* sW3v = reinterpret_cast<const float4*>(sW + O_W3);
    const float4* sB3v = reinterpret_cast<const float4*>(sW + O_B3);
    const float4* sW4v = reinterpret_cast<const float4*>(sW + O_W4);
    const float4* sB4v = reinterpret_cast<const float4*>(sW + O_B4);
    const float4* sW5v = reinterpret_cast<const float4*>(sW + O_W5);

    float4 hA0, hA1, hA2, hA3, hB0, hB1, hB2, hB3;
    float4 gA0, gA1, gA2, gA3, gB0, gB1, gB2, gB3;

    LAYER_FENCE();
    // ---- layer 1: 7 -> 16, relu ----
#define JG_L1(jg, dA, dB) {                                                  \
    float4 accA = sB1v[jg]; float4 accB = accA; float4 w;                    \
    w = sW1v[0 * 4 + (jg)]; FMA4(accA, w, p0x)  FMA4(accB, w, p1x)           \
    w = sW1v[1 * 4 + (jg)]; FMA4(accA, w, p0y)  FMA4(accB, w, p1y)           \
    w = sW1v[2 * 4 + (jg)]; FMA4(accA, w, p0z)  FMA4(accB, w, p1z)           \
    w = sW1v[3 * 4 + (jg)]; FMA4(accA, w, fA.x) FMA4(accB, w, fB.x)          \
    w = sW1v[4 * 4 + (jg)]; FMA4(accA, w, fA.y) FMA4(accB, w, fB.y)          \
    w = sW1v[5 * 4 + (jg)]; FMA4(accA, w, fA.z) FMA4(accB, w, fB.z)          \
    w = sW1v[6 * 4 + (jg)]; FMA4(accA, w, fA.w) FMA4(accB, w, fB.w)          \
    RELU4(accA) RELU4(accB) (dA) = accA; (dB) = accB; }

    JG_L1(0, hA0, hB0)
    JG_L1(1, hA1, hB1)
    JG_L1(2, hA2, hB2)
    JG_L1(3, hA3, hB3)
#undef JG_L1
    LAYER_FENCE();

    LAYER16S(sW2v, sB2v, hA0, hA1, hA2, hA3, hB0, hB1, hB2, hB3,
             gA0, gA1, gA2, gA3, gB0, gB1, gB2, gB3)
    LAYER_FENCE();
    LAYER16S(sW3v, sB3v, gA0, gA1, gA2, gA3, gB0, gB1, gB2, gB3,
             hA0, hA1, hA2, hA3, hB0, hB1, hB2, hB3)
    LAYER_FENCE();
    LAYER16S(sW4v, sB4v, hA0, hA1, hA2, hA3, hB0, hB1, hB2, hB3,
             gA0, gA1, gA2, gA3, gB0, gB1, gB2, gB3)
    LAYER_FENCE();

    // ---- layer 5: 16 -> 3 (padded to 4), no relu ----
    float4 oA = *reinterpret_cast<const float4*>(sW + O_B5);
    float4 oB = oA;
    {
        float4 w;
#define L5(idx, SA, SB, COMP)                                                \
        w = sW5v[idx];                                                       \
        oA.x = fmaf((SA).COMP, w.x, oA.x); oB.x = fmaf((SB).COMP, w.x, oB.x);\
        oA.y = fmaf((SA).COMP, w.y, oA.y); oB.y = fmaf((SB).COMP, w.y, oB.y);\
        oA.z = fmaf((SA).COMP, w.z, oA.z); oB.z = fmaf((SB).COMP, w.z, oB.z);
        L5( 0, gA0, gB0, x) L5( 1, gA0, gB0, y) L5( 2, gA0, gB0, z) L5( 3, gA0, gB0, w)
        L5( 4, gA1, gB1, x) L5( 5, gA1, gB1, y) L5( 6, gA1, gB1, z) L5( 7, gA1, gB1, w)
        L5( 8, gA2, gB2, x) L5( 9, gA2, gB2, y) L5(10, gA2, gB2, z) L5(11, gA2, gB2, w)
        L5(12, gA3, gB3, x) L5(13, gA3, gB3, y) L5(14, gA3, gB3, z) L5(15, gA3, gB3, w)
#undef L5
    }

    // ---- store ----
    if (have2) {
        float2* out2 = reinterpret_cast<float2*>(out);
        out2[3 * t]     = make_float2(oA.x, oA.y);
        out2[3 * t + 1] = make_float2(oA.z, oB.x);
        out2[3 * t + 2] = make_float2(oB.y, oB.z);
    } else {
        out[3 * i0] = oA.x; out[3 * i0 + 1] = oA.y; out[3 * i0 + 2] = oA.z;
    }
}

extern "C" void kernel_launch(void* const* d_in, const int* in_sizes, int n_in,
                              void* d_out, int out_size, void* d_ws, size_t ws_size,
                              hipStream_t stream) {
    const float* x  = (const float*)d_in[0];
    const float* fm = (const float*)d_in[1];
    const float* W1 = (const float*)d_in[2];
    const float* b1 = (const float*)d_in[3];
    const float* W2 = (const float*)d_in[4];
    const float* b2 = (const float*)d_in[5];
    const float* W3 = (const float*)d_in[6];
    const float* b3 = (const float*)d_in[7];
    const float* W4 = (const float*)d_in[8];
    const float* b4 = (const float*)d_in[9];
    const float* W5 = (const float*)d_in[10];
    const float* b5 = (const float*)d_in[11];
    float* out = (float*)d_out;

    const int n = in_sizes[0] / 3;  // 4,000,000 points
    const int block = 256;
    const long long threads = ((long long)n + 1) / 2;
    const int grid = (int)((threads + block - 1) / block);

    const size_t need = (size_t)HWSZ * 4 * sizeof(float);  // 4 MB
    if (ws_size >= need) {
        float* fmT = (float*)d_ws;
        fm_transpose<<<(HWSZ + 255) / 256, 256, 0, stream>>>(fm, fmT);
        mlp_fused<true><<<grid, block, 0, stream>>>(x, fmT, W1, b1, W2, b2, W3, b3,
                                                    W4, b4, W5, b5, out, n);
    } else {
        mlp_fused<false><<<grid, block, 0, stream>>>(x, fm, W1, b1, W2, b2, W3, b3,
                                                     W4, b4, W5, b5, out, n);
    }
}